// Round 16
// baseline (116.727 us; speedup 1.0000x reference)
//
#include <hip/hip_runtime.h>

// ---------------------------------------------------------------------------
// Fused pre-LN MHA block on MI355X (gfx950).
// B=2, L=2048, D=768, H=12, Dh=64.
// Pipeline: prep(LN+cvt) -> GEMM1 (qkv) -> flash-attn -> GEMM2+residual
// R15: attn 512-thr / 8 waves = 4 q-waves x 2 KV-HALVES; each half runs the
// proven R12 body on its own 16 tiles (identical frags/vmcnt/swizzles);
// one-time LDS merge epilogue.  80KB LDS -> 2 blocks/CU -> 16 waves/CU
// (was 12) to saturate the DS pipe.  Weight cvt vectorized (float4+cvt_pk).
// GEMMs unchanged (BK=32 dbuf, proven R14).
// ---------------------------------------------------------------------------

#define DEV __device__ __forceinline__

typedef __attribute__((ext_vector_type(4))) float f32x4;
typedef __attribute__((ext_vector_type(8))) short s16x8;
typedef __attribute__((ext_vector_type(2))) int i32x2;

constexpr int Bb   = 2;
constexpr int Ll   = 2048;
constexpr int Dd   = 768;
constexpr int Hh   = 12;
constexpr int Dh   = 64;
constexpr int Mrows = Bb * Ll;      // 4096
constexpr int N1   = 3 * Dd;        // 2304

DEV unsigned short f2bf(float f) {
  union { float f; unsigned u; } v; v.f = f;
  unsigned r = v.u + 0x7fffu + ((v.u >> 16) & 1u);
  return (unsigned short)(r >> 16);
}

DEV void gload_lds16(const void* g, void* l) {
  __builtin_amdgcn_global_load_lds((const __attribute__((address_space(1))) unsigned int*)g,
                                   (__attribute__((address_space(3))) unsigned int*)l,
                                   16, 0, 0);
}

DEV f32x4 mfma16(s16x8 a, s16x8 b, f32x4 c) {
  return __builtin_amdgcn_mfma_f32_16x16x32_bf16(a, b, c, 0, 0, 0);
}

// single-instruction 2^x and 1/x
DEV float fexp2(float x) { float r; asm("v_exp_f32 %0, %1" : "=v"(r) : "v"(x)); return r; }
DEV float frcp(float x)  { float r; asm("v_rcp_f32 %0, %1" : "=v"(r) : "v"(x)); return r; }

// reduce over lanes {l, l^16, l^32, l^48}: shfl for xor16, permlane32 for xor32
DEV float redmax64(float x) {
  x = fmaxf(x, __shfl_xor(x, 16, 64));
  float a = x, b = x;
  asm volatile("v_permlane32_swap_b32 %0, %1" : "+v"(a), "+v"(b));
  return fmaxf(a, b);
}
DEV float redsum64(float x) {
  x += __shfl_xor(x, 16, 64);
  float a = x, b = x;
  asm volatile("v_permlane32_swap_b32 %0, %1" : "+v"(a), "+v"(b));
  return a + b;
}

// ---------------------------------------------------------------------------
// LN body (one block per row, 256 thr)
// ---------------------------------------------------------------------------
DEV void ln_body(int row, int t, const float* __restrict__ x,
                 const float* __restrict__ gamma, const float* __restrict__ beta,
                 short* __restrict__ hbuf, float* red) {
  const float* xr = x + (size_t)row * Dd;
  float v0 = xr[t], v1 = xr[t + 256], v2 = xr[t + 512];
  float s = v0 + v1 + v2;
  float q = v0 * v0 + v1 * v1 + v2 * v2;
#pragma unroll
  for (int off = 32; off; off >>= 1) {
    s += __shfl_xor(s, off, 64);
    q += __shfl_xor(q, off, 64);
  }
  const int w = t >> 6, lane = t & 63;
  if (lane == 0) { red[w] = s; red[4 + w] = q; }
  __syncthreads();
  s = red[0] + red[1] + red[2] + red[3];
  q = red[4] + red[5] + red[6] + red[7];
  const float mean = s * (1.f / Dd);
  const float var  = q * (1.f / Dd) - mean * mean;
  const float rstd = rsqrtf(var + 1e-5f);
  short* hr = hbuf + (size_t)row * Dd;
  hr[t]       = (short)f2bf((v0 - mean) * rstd * gamma[t]       + beta[t]);
  hr[t + 256] = (short)f2bf((v1 - mean) * rstd * gamma[t + 256] + beta[t + 256]);
  hr[t + 512] = (short)f2bf((v2 - mean) * rstd * gamma[t + 512] + beta[t + 512]);
}

constexpr int W1E = N1 * Dd;     // 1769472
constexpr int W2E = Dd * Dd;     // 589824
constexpr int WV4 = (W1E + W2E) / 4;   // 589824 float4 groups (W1E%4==0)

// vectorized weight cvt body: float4 load, 2x cvt_pk, 8B store
DEV void cvt_v4(int i, const float* __restrict__ w1, const float* __restrict__ w2,
                short* __restrict__ w1b, short* __restrict__ w2b) {
  const int e = i * 4;
  const float* src = (e < W1E) ? (w1 + e) : (w2 + (e - W1E));
  short* dst       = (e < W1E) ? (w1b + e) : (w2b + (e - W1E));
  const f32x4 v = *(const f32x4*)src;
  unsigned u01, u23;
  asm("v_cvt_pk_bf16_f32 %0, %1, %2" : "=v"(u01) : "v"(v[0]), "v"(v[1]));
  asm("v_cvt_pk_bf16_f32 %0, %1, %2" : "=v"(u23) : "v"(v[2]), "v"(v[3]));
  i32x2 o; o[0] = (int)u01; o[1] = (int)u23;
  *(i32x2*)dst = o;
}

__global__ __launch_bounds__(256) void ln_kernel(const float* __restrict__ x,
                                                 const float* __restrict__ gamma,
                                                 const float* __restrict__ beta,
                                                 short* __restrict__ hbuf) {
  __shared__ float red[8];
  ln_body(blockIdx.x, threadIdx.x, x, gamma, beta, hbuf, red);
}

__global__ __launch_bounds__(256) void cvt_kernel(const float* __restrict__ w1,
                                                  const float* __restrict__ w2,
                                                  short* __restrict__ w1b,
                                                  short* __restrict__ w2b) {
  int i = blockIdx.x * 256 + threadIdx.x;
  const int stride = gridDim.x * 256;
  for (; i < WV4; i += stride) cvt_v4(i, w1, w2, w1b, w2b);
}

// fused LN (blocks 0..Mrows-1) + weight cvt (blocks Mrows..Mrows+1023)
__global__ __launch_bounds__(256) void prep_kernel(const float* __restrict__ x,
                                                   const float* __restrict__ gamma,
                                                   const float* __restrict__ beta,
                                                   short* __restrict__ hbuf,
                                                   const float* __restrict__ w1,
                                                   const float* __restrict__ w2,
                                                   short* __restrict__ w1b,
                                                   short* __restrict__ w2b) {
  __shared__ float red[8];
  if (blockIdx.x < (unsigned)Mrows) {
    ln_body(blockIdx.x, threadIdx.x, x, gamma, beta, hbuf, red);
  } else {
    int i = (blockIdx.x - Mrows) * 256 + threadIdx.x;
    for (; i < WV4; i += 1024 * 256) cvt_v4(i, w1, w2, w1b, w2b);
  }
}

// XCD-aware chunked swizzle of the linear block id (bijective when nwg%8==0).
DEV unsigned xcd_swz(unsigned f, unsigned nwg) {
  if ((nwg & 7u) != 0u) return f;
  return (f & 7u) * (nwg >> 3) + (f >> 3);
}

// ---------------------------------------------------------------------------
// GEMM (B^T form): C[m][n] = sum_k A[m][k] * W[n][k] (+bias)(+resid)
// 128x128 tile, 4 waves (2x2).
// WSRC 0: BK=32 double-buffered (32KB LDS -> 4 blocks/CU), counted vmcnt(4).
// WSRC 1 (fp32 weights, T3 tier): BK=64 single-buffer __syncthreads loop.
// ---------------------------------------------------------------------------
template <int EPI, int WSRC>
__global__ __launch_bounds__(256) void gemm_bt(const short* __restrict__ A,
                                               const void* __restrict__ Wp,
                                               const float* __restrict__ bias,
                                               const float* __restrict__ resid,
                                               void* __restrict__ outp,
                                               int N, int K) {
  __shared__ __align__(16) short As[2][WSRC == 0 ? 128 * 32 : 128 * 64];
  __shared__ __align__(16) short Ws[2][WSRC == 0 ? 128 * 32 : 128 * 64];
  const int tid  = threadIdx.x;
  const int lane = tid & 63, wid = tid >> 6;
  const int wr = wid >> 1, wc = wid & 1;
  const int g = lane >> 4, li = lane & 15;
  const unsigned o = xcd_swz(blockIdx.y * gridDim.x + blockIdx.x,
                             gridDim.x * gridDim.y);
  const int brow = (int)(o / gridDim.x) * 128, bcol = (int)(o % gridDim.x) * 128;

  f32x4 acc[4][4];
#pragma unroll
  for (int m = 0; m < 4; ++m)
#pragma unroll
    for (int n = 0; n < 4; ++n)
#pragma unroll
      for (int r = 0; r < 4; ++r) acc[m][n][r] = 0.f;

  if constexpr (WSRC == 0) {
    const short* W = (const short*)Wp;
    const int nt = K >> 5;                      // BK=32 tiles
    auto stage = [&](int t, int buf) {
      const int ko = t << 5;
#pragma unroll
      for (int i = 0; i < 2; ++i) {
        const int idx = i * 256 + tid;          // 0..511
        const int r = idx >> 2, c = idx & 3;
        const int cs = c ^ ((r >> 1) & 3);
        gload_lds16(A + (size_t)(brow + r) * K + ko + cs * 8,
                    (char*)&As[buf][0] + idx * 16);
        gload_lds16(W + (size_t)(bcol + r) * K + ko + cs * 8,
                    (char*)&Ws[buf][0] + idx * 16);
      }
    };
    stage(0, 0);
    stage(1, 1);
    for (int it = 0; it < nt; ++it) {
      const int cur = it & 1;
      if (it + 1 < nt) asm volatile("s_waitcnt vmcnt(4)" ::: "memory");
      else             asm volatile("s_waitcnt vmcnt(0)" ::: "memory");
      __builtin_amdgcn_s_barrier();
      __builtin_amdgcn_sched_barrier(0);
      {
        s16x8 af[4], bf[4];
        const int rsw = ((li >> 1) & 3);
#pragma unroll
        for (int m = 0; m < 4; ++m) {
          const int row = wr * 64 + m * 16 + li;
          af[m] = *(const s16x8*)((char*)&As[cur][0] + row * 64 + ((g ^ rsw) << 4));
        }
#pragma unroll
        for (int n = 0; n < 4; ++n) {
          const int row = wc * 64 + n * 16 + li;
          bf[n] = *(const s16x8*)((char*)&Ws[cur][0] + row * 64 + ((g ^ rsw) << 4));
        }
#pragma unroll
        for (int m = 0; m < 4; ++m)
#pragma unroll
          for (int n = 0; n < 4; ++n)
            acc[m][n] = mfma16(af[m], bf[n], acc[m][n]);
      }
      __builtin_amdgcn_s_barrier();
      if (it + 2 < nt) stage(it + 2, cur);
    }
  } else {
    const float* W = (const float*)Wp;
    for (int kt = 0; kt < K; kt += 64) {
#pragma unroll
      for (int i = 0; i < 4; ++i) {
        const int idx = i * 256 + tid;
        const int r = idx >> 3, c = idx & 7;
        const int cs = c ^ (r & 7);
        gload_lds16(A + (size_t)(brow + r) * K + kt + cs * 8,
                    (char*)&As[0][0] + idx * 16);
      }
#pragma unroll
      for (int i = 0; i < 4; ++i) {
        const int idx = i * 256 + tid;
        const int r = idx >> 3, c = idx & 7;
        const float* wp = W + (size_t)(bcol + r) * K + kt + c * 8;
        const f32x4 lo = *(const f32x4*)wp;
        const f32x4 hi = *(const f32x4*)(wp + 4);
        s16x8 oo;
#pragma unroll
        for (int j = 0; j < 4; ++j) {
          oo[j]     = (short)f2bf(lo[j]);
          oo[4 + j] = (short)f2bf(hi[j]);
        }
        *(s16x8*)((char*)&Ws[0][0] + (size_t)(r * 8 + (c ^ (r & 7))) * 16) = oo;
      }
      __syncthreads();
#pragma unroll
      for (int kk = 0; kk < 2; ++kk) {
        s16x8 af[4], bf[4];
#pragma unroll
        for (int m = 0; m < 4; ++m) {
          const int row = wr * 64 + m * 16 + li;
          af[m] = *(const s16x8*)&As[0][row * 64 + (((kk * 4 + g) ^ (li & 7)) & 7) * 8];
        }
#pragma unroll
        for (int n = 0; n < 4; ++n) {
          const int row = wc * 64 + n * 16 + li;
          bf[n] = *(const s16x8*)&Ws[0][row * 64 + (((kk * 4 + g) ^ (li & 7)) & 7) * 8];
        }
#pragma unroll
        for (int m = 0; m < 4; ++m)
#pragma unroll
          for (int n = 0; n < 4; ++n)
            acc[m][n] = mfma16(af[m], bf[n], acc[m][n]);
      }
      __syncthreads();
    }
  }

#pragma unroll
  for (int m = 0; m < 4; ++m) {
#pragma unroll
    for (int n = 0; n < 4; ++n) {
      const int col = bcol + wc * 64 + n * 16 + li;
      const float bv = bias[col];
#pragma unroll
      for (int r = 0; r < 4; ++r) {
        const int row = brow + wr * 64 + m * 16 + g * 4 + r;
        const float v = acc[m][n][r] + bv;
        if (EPI == 0) {
          ((short*)outp)[(size_t)row * N + col] = (short)f2bf(v);
        } else {
          const size_t o2 = (size_t)row * N + col;
          ((float*)outp)[o2] = v + resid[o2];
        }
      }
    }
  }
}

// ---------------------------------------------------------------------------
// Flash attention R15.  Grid (32, nb*12), 512 thr = 8 waves.
// wave w: q-sub wq=w&3 (16 rows), kv-half kvh=w>>2 (16 tiles of 64 kv).
// Each half runs the R12 body on its own double-buffered K/V (identical
// fragment maps / vmcnt(2) counts / swizzles).  LDS 80KB -> 2 blocks/CU.
// Epilogue: exact 2-way online-softmax merge via LDS (half1 -> half0).
// ---------------------------------------------------------------------------
#define TRRD(dst, addr, OFF)                                                   \
  asm volatile("ds_read_b64_tr_b16 %0, %1 offset:" #OFF                        \
               : "=v"(dst) : "v"(addr))

__global__ __launch_bounds__(512) void attn_kernel(const short* __restrict__ qkv,
                                                   short* __restrict__ obuf) {
  __shared__ __align__(16) short Ks[4][64 * 64];   // [kvh*2+buf]
  __shared__ __align__(16) short Vt[4][64 * 64];
  __shared__ __align__(16) short Ps[8][16 * 64];
  const int tid  = threadIdx.x;
  const int lane = tid & 63, w = tid >> 6;
  const int wq = w & 3, kvh = w >> 2;
  const int g = lane >> 4, li = lane & 15;
  const unsigned o = xcd_swz(blockIdx.y * 32u + blockIdx.x, gridDim.x * gridDim.y);
  const int bh = (int)(o >> 5);
  const int b = bh / Hh, h = bh % Hh;
  const size_t rowbase = (size_t)b * Ll * N1;
  const int q0 = (int)(o & 31u) * 64 + wq * 16;
  constexpr float kScale = 0.125f * 1.44269504f;   // 1/sqrt(Dh) * log2(e)
  constexpr float kThrRaw = 8.f / kScale;          // defer-max threshold (raw)
  constexpr int KVSTRIDE = 64 * N1;                // elements per KV tile
  constexpr int NT2 = 16;                          // tiles per kv-half

  // Q fragments (B operand of swapped QK^T)
  s16x8 qf[2];
#pragma unroll
  for (int ks = 0; ks < 2; ++ks)
    qf[ks] = *(const s16x8*)(qkv + rowbase + (size_t)(q0 + li) * N1 +
                             h * Dh + ks * 32 + g * 8);

  f32x4 oa[4];
  float m_ = -1e30f, l_ = 0.f;   // m_ row-uniform (raw); l_ per-lane PARTIAL
#pragma unroll
  for (int dn = 0; dn < 4; ++dn)
#pragma unroll
    for (int r = 0; r < 4; ++r) oa[dn][r] = 0.f;

  // ---- hoisted staging source pointers (each wave stages its own half) ----
  const int lt = tid & 255;                        // local thread within half
  const int ia = lt, ib = 256 + lt;
  const int ra = ia >> 3, ca = ia & 7, rb = ib >> 3, cb = ib & 7;
  const size_t hb0 = rowbase + (size_t)(kvh * NT2) * KVSTRIDE;
  const short* kpa = qkv + hb0 + Dd + h * Dh + (size_t)ra * N1 + (ca ^ (ra & 7)) * 8;
  const short* kpb = qkv + hb0 + Dd + h * Dh + (size_t)rb * N1 + (cb ^ (rb & 7)) * 8;
  const int Ta = ia >> 3, Tb = ib >> 3;
  const short* vpa = qkv + hb0 + 2 * Dd + h * Dh +
                     (size_t)((Ta & 15) * 4 + (ca >> 1)) * N1 + (Ta >> 4) * 16 + (ia & 1) * 8;
  const short* vpb = qkv + hb0 + 2 * Dd + h * Dh +
                     (size_t)((Tb & 15) * 4 + (cb >> 1)) * N1 + (Tb >> 4) * 16 + (ib & 1) * 8;
  char* KsB = (char*)&Ks[0][0] + (kvh << 14);      // this half's 16 KB region
  char* VtB = (char*)&Vt[0][0] + (kvh << 14);
  const int dsta = ia * 16, dstb = ib * 16;

  // ---- hoisted LDS fragment offsets (bytes) ----
  int koff[4][2];
#pragma unroll
  for (int n = 0; n < 4; ++n) {
    koff[n][0] = ((n * 16 + li) * 64 + ((g ^ (li & 7)) & 7) * 8) * 2;
    koff[n][1] = ((n * 16 + li) * 64 + (((4 + g) ^ (li & 7)) & 7) * 8) * 2;
  }
  int pwoff[4], proff[2];
#pragma unroll
  for (int n = 0; n < 4; ++n)
    pwoff[n] = li * 128 + (((2 * n + (g >> 1)) ^ (li & 7)) << 4) + 8 * (g & 1);
#pragma unroll
  for (int kk = 0; kk < 2; ++kk)
    proff[kk] = li * 128 + (((4 * kk + g) ^ (li & 7)) << 4);
  char* Pw = (char*)&Ps[w][0];
  const unsigned vlane = (unsigned)((lane >> 4) * 256 + (lane & 15) * 2);
  const unsigned vbase0 = (unsigned)(unsigned long long)VtB + vlane;

  auto stageK = [&](int buf) {
    const int bo = buf << 13;
    gload_lds16(kpa, KsB + bo + dsta);
    gload_lds16(kpb, KsB + bo + dstb);
    kpa += KVSTRIDE; kpb += KVSTRIDE;
  };
  auto stageV = [&](int buf) {
    const int bo = buf << 13;
    gload_lds16(vpa, VtB + bo + dsta);
    gload_lds16(vpb, VtB + bo + dstb);
    vpa += KVSTRIDE; vpb += KVSTRIDE;
  };

  // prologue: K0 V0 K1 V1 (8 loads); wait K0+V0, leave K1+V1 in flight
  stageK(0); stageV(0); stageK(1); stageV(1);
  asm volatile("s_waitcnt vmcnt(4)" ::: "memory");
  __builtin_amdgcn_s_barrier();
  __builtin_amdgcn_sched_barrier(0);

  f32x4 zA[4], zB[4];
#pragma unroll
  for (int n = 0; n < 4; ++n) {
    s16x8 kf0 = *(const s16x8*)(KsB + koff[n][0]);
    s16x8 kf1 = *(const s16x8*)(KsB + koff[n][1]);
    f32x4 z;
#pragma unroll
    for (int r = 0; r < 4; ++r) z[r] = 0.f;
    z = mfma16(kf0, qf[0], z);
    z = mfma16(kf1, qf[1], z);
    zA[n] = z;
  }

  // one iteration body: local tile kt (buffer cur), scores zC; zN for kt+1
  auto body = [&](int kt, int cur, f32x4 (&zC)[4], f32x4 (&zN)[4]) {
    const int curo = cur << 13;
    const int nxto = (cur ^ 1) << 13;
    if (kt + 1 < NT2) asm volatile("s_waitcnt vmcnt(2)" ::: "memory");
    else              asm volatile("s_waitcnt vmcnt(0)" ::: "memory");
    __builtin_amdgcn_s_barrier();
    __builtin_amdgcn_sched_barrier(0);

    if (kt + 2 < NT2) stageK(cur);

    if (kt + 1 < NT2) {
      __builtin_amdgcn_s_setprio(1);
#pragma unroll
      for (int n = 0; n < 4; ++n) {
        s16x8 kf0 = *(const s16x8*)(KsB + nxto + koff[n][0]);
        s16x8 kf1 = *(const s16x8*)(KsB + nxto + koff[n][1]);
        f32x4 z;
#pragma unroll
        for (int r = 0; r < 4; ++r) z[r] = 0.f;
        z = mfma16(kf0, qf[0], z);
        z = mfma16(kf1, qf[1], z);
        zN[n] = z;
      }
      __builtin_amdgcn_s_setprio(0);
    }

    // ---- softmax on zC: per-lane local max checks the defer branch ----
    const float t0 = fmaxf(fmaxf(zC[0][0], zC[0][1]), zC[0][2]);
    const float t1 = fmaxf(fmaxf(zC[0][3], zC[1][0]), zC[1][1]);
    const float t2 = fmaxf(fmaxf(zC[1][2], zC[1][3]), zC[2][0]);
    const float t3 = fmaxf(fmaxf(zC[2][1], zC[2][2]), zC[2][3]);
    const float t4 = fmaxf(fmaxf(zC[3][0], zC[3][1]), zC[3][2]);
    const float mloc = fmaxf(fmaxf(fmaxf(fmaxf(t0, t1), t2), fmaxf(t3, t4)), zC[3][3]);
    if (!__all(mloc - m_ <= kThrRaw)) {
      const float mxr = redmax64(mloc);          // full row max (rare path)
      const float mnew = fmaxf(m_, mxr);
      const float sc = fexp2((m_ - mnew) * kScale);
      float scq[4];
#pragma unroll
      for (int r = 0; r < 4; ++r)
        scq[r] = __shfl(sc, (lane & 48) + ((lane & 48) >> 2) + r, 64);
#pragma unroll
      for (int dn = 0; dn < 4; ++dn)
#pragma unroll
        for (int r = 0; r < 4; ++r) oa[dn][r] *= scq[r];
      l_ *= sc;
      m_ = mnew;
    }
    const float msc = m_ * kScale;
#pragma unroll
    for (int n = 0; n < 4; ++n)
#pragma unroll
      for (int r = 0; r < 4; ++r) {
        const float p = fexp2(fmaf(zC[n][r], kScale, -msc));
        zC[n][r] = p;
        l_ += p;
      }

    // ---- P pack via cvt_pk -> swizzled per-wave LDS (4 x ds_write_b64) ----
#pragma unroll
    for (int n = 0; n < 4; ++n) {
      unsigned u0, u1;
      asm("v_cvt_pk_bf16_f32 %0, %1, %2" : "=v"(u0) : "v"(zC[n][0]), "v"(zC[n][1]));
      asm("v_cvt_pk_bf16_f32 %0, %1, %2" : "=v"(u1) : "v"(zC[n][2]), "v"(zC[n][3]));
      i32x2 pv; pv[0] = (int)u0; pv[1] = (int)u1;
      *(i32x2*)(Pw + pwoff[n]) = pv;
    }

    s16x8 pf[2];
#pragma unroll
    for (int kk = 0; kk < 2; ++kk)
      pf[kk] = *(const s16x8*)(Pw + proff[kk]);

    union VU { long l[2]; s16x8 v; };
    VU vu[4][2];
    {
      const unsigned vaddr = vbase0 + (unsigned)curo;
      TRRD(vu[0][0].l[0], vaddr, 0);    TRRD(vu[0][0].l[1], vaddr, 128);
      TRRD(vu[0][1].l[0], vaddr, 1024); TRRD(vu[0][1].l[1], vaddr, 1152);
      TRRD(vu[1][0].l[0], vaddr, 2048); TRRD(vu[1][0].l[1], vaddr, 2176);
      TRRD(vu[1][1].l[0], vaddr, 3072); TRRD(vu[1][1].l[1], vaddr, 3200);
      TRRD(vu[2][0].l[0], vaddr, 4096); TRRD(vu[2][0].l[1], vaddr, 4224);
      TRRD(vu[2][1].l[0], vaddr, 5120); TRRD(vu[2][1].l[1], vaddr, 5248);
      TRRD(vu[3][0].l[0], vaddr, 6144); TRRD(vu[3][0].l[1], vaddr, 6272);
      TRRD(vu[3][1].l[0], vaddr, 7168); TRRD(vu[3][1].l[1], vaddr, 7296);
    }
    asm volatile("s_waitcnt lgkmcnt(0)" ::: "memory");
    __builtin_amdgcn_sched_barrier(0);

    __builtin_amdgcn_s_setprio(1);
#pragma unroll
    for (int dn = 0; dn < 4; ++dn) {
      oa[dn] = mfma16(pf[0], vu[dn][0].v, oa[dn]);
      oa[dn] = mfma16(pf[1], vu[dn][1].v, oa[dn]);
    }
    __builtin_amdgcn_s_setprio(0);

    __builtin_amdgcn_s_barrier();
    if (kt + 2 < NT2) stageV(cur);
  };

  // unrolled x2: even tile buf0 (zA->zB), odd tile buf1 (zB->zA)
  for (int g2 = 0; g2 < NT2 / 2; ++g2) {
    body(2 * g2,     0, zA, zB);
    body(2 * g2 + 1, 1, zB, zA);
  }

  // ---- merge the two kv-halves (exact 2-way online-softmax combine) ----
  l_ = redsum64(l_);                 // per-lane l for q=li (replicated over g)
  __syncthreads();                   // all waves done with K/V LDS
  float* MO = (float*)&Ks[0][0];     // [wq][qr][d] : 4*16*64 f32 = 16 KB
  float* MM = (float*)&Vt[0][0];     // m at [wq*16+q], l at [64+wq*16+q]
  if (kvh == 1) {
#pragma unroll
    for (int dn = 0; dn < 4; ++dn)
#pragma unroll
      for (int r = 0; r < 4; ++r)
        MO[wq * 1024 + (g * 4 + r) * 64 + dn * 16 + li] = oa[dn][r];
    if (g == 0) {
      MM[wq * 16 + li] = m_;
      MM[64 + wq * 16 + li] = l_;
    }
  }
  __syncthreads();
  if (kvh == 0) {
#pragma unroll
    for (int r = 0; r < 4; ++r) {
      const int qr = g * 4 + r;
      const float m0 = __shfl(m_, (lane & 48) + qr, 64);
      const float l0 = __shfl(l_, (lane & 48) + qr, 64);
      const float m1 = MM[wq * 16 + qr];
      const float l1 = MM[64 + wq * 16 + qr];
      const float mm = fmaxf(m0, m1);
      const float s0 = fexp2((m0 - mm) * kScale);
      const float s1 = fexp2((m1 - mm) * kScale);
      const float inv = frcp(l0 * s0 + l1 * s1);
      const int row = b * Ll + q0 + qr;
#pragma unroll
      for (int dn = 0; dn < 4; ++dn) {
        const float o1 = MO[wq * 1024 + qr * 64 + dn * 16 + li];
        obuf[(size_t)row * Dd + h * Dh + dn * 16 + li] =
            (short)f2bf((oa[dn][r] * s0 + o1 * s1) * inv);
      }
    }
  }
}

// ---------------------------------------------------------------------------
extern "C" void kernel_launch(void* const* d_in, const int* in_sizes, int n_in,
                              void* d_out, int out_size, void* d_ws, size_t ws_size,
                              hipStream_t stream) {
  const float* x     = (const float*)d_in[0];
  const float* gamma = (const float*)d_in[1];
  const float* beta  = (const float*)d_in[2];
  const float* w1    = (const float*)d_in[3];
  const float* b1    = (const float*)d_in[4];
  const float* w2    = (const float*)d_in[5];
  const float* b2    = (const float*)d_in[6];
  float* out = (float*)d_out;
  char* ws = (char*)d_ws;

  if (ws_size >= 29884416) {
    // ---- T1: full batch in one pass.  ws = 29,884,416 B ----
    short* qkvb = (short*)(ws);              // 4096*2304*2 = 18874368
    short* hb   = (short*)(ws + 18874368);   // 4096*768*2  = 6291456 (hbuf, then obuf)
    short* w1b  = (short*)(ws + 25165824);   // 2304*768*2  = 3538944
    short* w2b  = (short*)(ws + 28704768);   // 768*768*2   = 1179648
    prep_kernel<<<dim3(Mrows + 1024), dim3(256), 0, stream>>>(
        x, gamma, beta, hb, w1, w2, w1b, w2b);
    gemm_bt<0, 0><<<dim3(N1 / 128, Mrows / 128), dim3(256), 0, stream>>>(
        hb, w1b, b1, nullptr, (void*)qkvb, N1, Dd);
    attn_kernel<<<dim3(Ll / 64, Bb * Hh), dim3(512), 0, stream>>>(qkvb, hb);
    gemm_bt<1, 0><<<dim3(Dd / 128, Mrows / 128), dim3(256), 0, stream>>>(
        hb, w2b, b2, x, (void*)out, Dd, Dd);
  } else if (ws_size >= 17301504) {
    // ---- T2: per-batch, bf16 weights.  ws = 17,301,504 B ----
    short* qkvb = (short*)(ws);              // 2048*2304*2 = 9437184
    short* hb   = (short*)(ws + 9437184);    // 2048*768*2  = 3145728 (hbuf/obuf)
    short* w1b  = (short*)(ws + 12582912);   // 3538944
    short* w2b  = (short*)(ws + 16121856);   // 1179648
    cvt_kernel<<<dim3(1024), dim3(256), 0, stream>>>(w1, w2, w1b, w2b);
    for (int b = 0; b < Bb; ++b) {
      const size_t ro = (size_t)b * Ll * Dd;
      ln_kernel<<<dim3(Ll), dim3(256), 0, stream>>>(x + ro, gamma, beta, hb);
      gemm_bt<0, 0><<<dim3(N1 / 128, Ll / 128), dim3(256), 0, stream>>>(
          hb, w1b, b1, nullptr, (void*)qkvb, N1, Dd);
      attn_kernel<<<dim3(Ll / 64, Hh), dim3(512), 0, stream>>>(qkvb, hb);
      gemm_bt<1, 0><<<dim3(Dd / 128, Ll / 128), dim3(256), 0, stream>>>(
          hb, w2b, b2, x + ro, (void*)(out + ro), Dd, Dd);
    }
  } else {
    // ---- T3: per-batch, fp32 weights staged on the fly.  ws = 12,582,912 B ----
    short* qkvb = (short*)(ws);              // 9437184
    short* hb   = (short*)(ws + 9437184);    // 3145728 (hbuf/obuf)
    for (int b = 0; b < Bb; ++b) {
      const size_t ro = (size_t)b * Ll * Dd;
      ln_kernel<<<dim3(Ll), dim3(256), 0, stream>>>(x + ro, gamma, beta, hb);
      gemm_bt<0, 1><<<dim3(N1 / 128, Ll / 128), dim3(256), 0, stream>>>(
          hb, w1, b1, nullptr, (void*)qkvb, N1, Dd);
      attn_kernel<<<dim3(Ll / 64, Hh), dim3(512), 0, stream>>>(qkvb, hb);
      gemm_bt<1, 1><<<dim3(Dd / 128, Ll / 128), dim3(256), 0, stream>>>(
          hb, w2, b2, x + ro, (void*)(out + ro), Dd, Dd);
    }
  }
}

// Round 17
// 100.326 us; speedup vs baseline: 1.1635x; 1.1635x over previous
//
#include <hip/hip_runtime.h>

// ---------------------------------------------------------------------------
// Fused pre-LN MHA block on MI355X (gfx950).
// B=2, L=2048, D=768, H=12, Dh=64.
// Pipeline: prep(LN+cvt) -> GEMM1 (qkv) -> flash-attn -> GEMM2+residual
// R16: revert attn to the proven R12 body (4 waves x 16q, 768 blocks,
// counted vmcnt(2), zA/zB, local-check defer-max, partial-l, unroll-2) —
// the kv-split-512 experiment regressed (block-wide barriers couple halves).
// Keep R14 GEMM (BK=32 dbuf, 4 blocks/CU) + R15 vectorized weight cvt.
// ---------------------------------------------------------------------------

#define DEV __device__ __forceinline__

typedef __attribute__((ext_vector_type(4))) float f32x4;
typedef __attribute__((ext_vector_type(8))) short s16x8;
typedef __attribute__((ext_vector_type(2))) int i32x2;

constexpr int Bb   = 2;
constexpr int Ll   = 2048;
constexpr int Dd   = 768;
constexpr int Hh   = 12;
constexpr int Dh   = 64;
constexpr int Mrows = Bb * Ll;      // 4096
constexpr int N1   = 3 * Dd;        // 2304

DEV unsigned short f2bf(float f) {
  union { float f; unsigned u; } v; v.f = f;
  unsigned r = v.u + 0x7fffu + ((v.u >> 16) & 1u);
  return (unsigned short)(r >> 16);
}

DEV void gload_lds16(const void* g, void* l) {
  __builtin_amdgcn_global_load_lds((const __attribute__((address_space(1))) unsigned int*)g,
                                   (__attribute__((address_space(3))) unsigned int*)l,
                                   16, 0, 0);
}

DEV f32x4 mfma16(s16x8 a, s16x8 b, f32x4 c) {
  return __builtin_amdgcn_mfma_f32_16x16x32_bf16(a, b, c, 0, 0, 0);
}

// single-instruction 2^x and 1/x
DEV float fexp2(float x) { float r; asm("v_exp_f32 %0, %1" : "=v"(r) : "v"(x)); return r; }
DEV float frcp(float x)  { float r; asm("v_rcp_f32 %0, %1" : "=v"(r) : "v"(x)); return r; }

// reduce over lanes {l, l^16, l^32, l^48}: shfl for xor16, permlane32 for xor32
DEV float redmax64(float x) {
  x = fmaxf(x, __shfl_xor(x, 16, 64));
  float a = x, b = x;
  asm volatile("v_permlane32_swap_b32 %0, %1" : "+v"(a), "+v"(b));
  return fmaxf(a, b);
}
DEV float redsum64(float x) {
  x += __shfl_xor(x, 16, 64);
  float a = x, b = x;
  asm volatile("v_permlane32_swap_b32 %0, %1" : "+v"(a), "+v"(b));
  return a + b;
}

// ---------------------------------------------------------------------------
// LN body (one block per row, 256 thr)
// ---------------------------------------------------------------------------
DEV void ln_body(int row, int t, const float* __restrict__ x,
                 const float* __restrict__ gamma, const float* __restrict__ beta,
                 short* __restrict__ hbuf, float* red) {
  const float* xr = x + (size_t)row * Dd;
  float v0 = xr[t], v1 = xr[t + 256], v2 = xr[t + 512];
  float s = v0 + v1 + v2;
  float q = v0 * v0 + v1 * v1 + v2 * v2;
#pragma unroll
  for (int off = 32; off; off >>= 1) {
    s += __shfl_xor(s, off, 64);
    q += __shfl_xor(q, off, 64);
  }
  const int w = t >> 6, lane = t & 63;
  if (lane == 0) { red[w] = s; red[4 + w] = q; }
  __syncthreads();
  s = red[0] + red[1] + red[2] + red[3];
  q = red[4] + red[5] + red[6] + red[7];
  const float mean = s * (1.f / Dd);
  const float var  = q * (1.f / Dd) - mean * mean;
  const float rstd = rsqrtf(var + 1e-5f);
  short* hr = hbuf + (size_t)row * Dd;
  hr[t]       = (short)f2bf((v0 - mean) * rstd * gamma[t]       + beta[t]);
  hr[t + 256] = (short)f2bf((v1 - mean) * rstd * gamma[t + 256] + beta[t + 256]);
  hr[t + 512] = (short)f2bf((v2 - mean) * rstd * gamma[t + 512] + beta[t + 512]);
}

constexpr int W1E = N1 * Dd;     // 1769472
constexpr int W2E = Dd * Dd;     // 589824
constexpr int WV4 = (W1E + W2E) / 4;   // 589824 float4 groups (W1E%4==0)

// vectorized weight cvt body: float4 load, 2x cvt_pk, 8B store
DEV void cvt_v4(int i, const float* __restrict__ w1, const float* __restrict__ w2,
                short* __restrict__ w1b, short* __restrict__ w2b) {
  const int e = i * 4;
  const float* src = (e < W1E) ? (w1 + e) : (w2 + (e - W1E));
  short* dst       = (e < W1E) ? (w1b + e) : (w2b + (e - W1E));
  const f32x4 v = *(const f32x4*)src;
  unsigned u01, u23;
  asm("v_cvt_pk_bf16_f32 %0, %1, %2" : "=v"(u01) : "v"(v[0]), "v"(v[1]));
  asm("v_cvt_pk_bf16_f32 %0, %1, %2" : "=v"(u23) : "v"(v[2]), "v"(v[3]));
  i32x2 o; o[0] = (int)u01; o[1] = (int)u23;
  *(i32x2*)dst = o;
}

__global__ __launch_bounds__(256) void ln_kernel(const float* __restrict__ x,
                                                 const float* __restrict__ gamma,
                                                 const float* __restrict__ beta,
                                                 short* __restrict__ hbuf) {
  __shared__ float red[8];
  ln_body(blockIdx.x, threadIdx.x, x, gamma, beta, hbuf, red);
}

__global__ __launch_bounds__(256) void cvt_kernel(const float* __restrict__ w1,
                                                  const float* __restrict__ w2,
                                                  short* __restrict__ w1b,
                                                  short* __restrict__ w2b) {
  int i = blockIdx.x * 256 + threadIdx.x;
  const int stride = gridDim.x * 256;
  for (; i < WV4; i += stride) cvt_v4(i, w1, w2, w1b, w2b);
}

// fused LN (blocks 0..Mrows-1) + weight cvt (blocks Mrows..Mrows+1023)
__global__ __launch_bounds__(256) void prep_kernel(const float* __restrict__ x,
                                                   const float* __restrict__ gamma,
                                                   const float* __restrict__ beta,
                                                   short* __restrict__ hbuf,
                                                   const float* __restrict__ w1,
                                                   const float* __restrict__ w2,
                                                   short* __restrict__ w1b,
                                                   short* __restrict__ w2b) {
  __shared__ float red[8];
  if (blockIdx.x < (unsigned)Mrows) {
    ln_body(blockIdx.x, threadIdx.x, x, gamma, beta, hbuf, red);
  } else {
    int i = (blockIdx.x - Mrows) * 256 + threadIdx.x;
    for (; i < WV4; i += 1024 * 256) cvt_v4(i, w1, w2, w1b, w2b);
  }
}

// XCD-aware chunked swizzle of the linear block id (bijective when nwg%8==0).
DEV unsigned xcd_swz(unsigned f, unsigned nwg) {
  if ((nwg & 7u) != 0u) return f;
  return (f & 7u) * (nwg >> 3) + (f >> 3);
}

// ---------------------------------------------------------------------------
// GEMM (B^T form): C[m][n] = sum_k A[m][k] * W[n][k] (+bias)(+resid)
// 128x128 tile, 4 waves (2x2).
// WSRC 0: BK=32 double-buffered (32KB LDS -> 4 blocks/CU), counted vmcnt(4).
// WSRC 1 (fp32 weights, T3 tier): BK=64 single-buffer __syncthreads loop.
// ---------------------------------------------------------------------------
template <int EPI, int WSRC>
__global__ __launch_bounds__(256) void gemm_bt(const short* __restrict__ A,
                                               const void* __restrict__ Wp,
                                               const float* __restrict__ bias,
                                               const float* __restrict__ resid,
                                               void* __restrict__ outp,
                                               int N, int K) {
  __shared__ __align__(16) short As[2][WSRC == 0 ? 128 * 32 : 128 * 64];
  __shared__ __align__(16) short Ws[2][WSRC == 0 ? 128 * 32 : 128 * 64];
  const int tid  = threadIdx.x;
  const int lane = tid & 63, wid = tid >> 6;
  const int wr = wid >> 1, wc = wid & 1;
  const int g = lane >> 4, li = lane & 15;
  const unsigned o = xcd_swz(blockIdx.y * gridDim.x + blockIdx.x,
                             gridDim.x * gridDim.y);
  const int brow = (int)(o / gridDim.x) * 128, bcol = (int)(o % gridDim.x) * 128;

  f32x4 acc[4][4];
#pragma unroll
  for (int m = 0; m < 4; ++m)
#pragma unroll
    for (int n = 0; n < 4; ++n)
#pragma unroll
      for (int r = 0; r < 4; ++r) acc[m][n][r] = 0.f;

  if constexpr (WSRC == 0) {
    const short* W = (const short*)Wp;
    const int nt = K >> 5;                      // BK=32 tiles
    auto stage = [&](int t, int buf) {
      const int ko = t << 5;
#pragma unroll
      for (int i = 0; i < 2; ++i) {
        const int idx = i * 256 + tid;          // 0..511
        const int r = idx >> 2, c = idx & 3;
        const int cs = c ^ ((r >> 1) & 3);
        gload_lds16(A + (size_t)(brow + r) * K + ko + cs * 8,
                    (char*)&As[buf][0] + idx * 16);
        gload_lds16(W + (size_t)(bcol + r) * K + ko + cs * 8,
                    (char*)&Ws[buf][0] + idx * 16);
      }
    };
    stage(0, 0);
    stage(1, 1);
    for (int it = 0; it < nt; ++it) {
      const int cur = it & 1;
      if (it + 1 < nt) asm volatile("s_waitcnt vmcnt(4)" ::: "memory");
      else             asm volatile("s_waitcnt vmcnt(0)" ::: "memory");
      __builtin_amdgcn_s_barrier();
      __builtin_amdgcn_sched_barrier(0);
      {
        s16x8 af[4], bf[4];
        const int rsw = ((li >> 1) & 3);
#pragma unroll
        for (int m = 0; m < 4; ++m) {
          const int row = wr * 64 + m * 16 + li;
          af[m] = *(const s16x8*)((char*)&As[cur][0] + row * 64 + ((g ^ rsw) << 4));
        }
#pragma unroll
        for (int n = 0; n < 4; ++n) {
          const int row = wc * 64 + n * 16 + li;
          bf[n] = *(const s16x8*)((char*)&Ws[cur][0] + row * 64 + ((g ^ rsw) << 4));
        }
#pragma unroll
        for (int m = 0; m < 4; ++m)
#pragma unroll
          for (int n = 0; n < 4; ++n)
            acc[m][n] = mfma16(af[m], bf[n], acc[m][n]);
      }
      __builtin_amdgcn_s_barrier();
      if (it + 2 < nt) stage(it + 2, cur);
    }
  } else {
    const float* W = (const float*)Wp;
    for (int kt = 0; kt < K; kt += 64) {
#pragma unroll
      for (int i = 0; i < 4; ++i) {
        const int idx = i * 256 + tid;
        const int r = idx >> 3, c = idx & 7;
        const int cs = c ^ (r & 7);
        gload_lds16(A + (size_t)(brow + r) * K + kt + cs * 8,
                    (char*)&As[0][0] + idx * 16);
      }
#pragma unroll
      for (int i = 0; i < 4; ++i) {
        const int idx = i * 256 + tid;
        const int r = idx >> 3, c = idx & 7;
        const float* wp = W + (size_t)(bcol + r) * K + kt + c * 8;
        const f32x4 lo = *(const f32x4*)wp;
        const f32x4 hi = *(const f32x4*)(wp + 4);
        s16x8 oo;
#pragma unroll
        for (int j = 0; j < 4; ++j) {
          oo[j]     = (short)f2bf(lo[j]);
          oo[4 + j] = (short)f2bf(hi[j]);
        }
        *(s16x8*)((char*)&Ws[0][0] + (size_t)(r * 8 + (c ^ (r & 7))) * 16) = oo;
      }
      __syncthreads();
#pragma unroll
      for (int kk = 0; kk < 2; ++kk) {
        s16x8 af[4], bf[4];
#pragma unroll
        for (int m = 0; m < 4; ++m) {
          const int row = wr * 64 + m * 16 + li;
          af[m] = *(const s16x8*)&As[0][row * 64 + (((kk * 4 + g) ^ (li & 7)) & 7) * 8];
        }
#pragma unroll
        for (int n = 0; n < 4; ++n) {
          const int row = wc * 64 + n * 16 + li;
          bf[n] = *(const s16x8*)&Ws[0][row * 64 + (((kk * 4 + g) ^ (li & 7)) & 7) * 8];
        }
#pragma unroll
        for (int m = 0; m < 4; ++m)
#pragma unroll
          for (int n = 0; n < 4; ++n)
            acc[m][n] = mfma16(af[m], bf[n], acc[m][n]);
      }
      __syncthreads();
    }
  }

#pragma unroll
  for (int m = 0; m < 4; ++m) {
#pragma unroll
    for (int n = 0; n < 4; ++n) {
      const int col = bcol + wc * 64 + n * 16 + li;
      const float bv = bias[col];
#pragma unroll
      for (int r = 0; r < 4; ++r) {
        const int row = brow + wr * 64 + m * 16 + g * 4 + r;
        const float v = acc[m][n][r] + bv;
        if (EPI == 0) {
          ((short*)outp)[(size_t)row * N + col] = (short)f2bf(v);
        } else {
          const size_t o2 = (size_t)row * N + col;
          ((float*)outp)[o2] = v + resid[o2];
        }
      }
    }
  }
}

// ---------------------------------------------------------------------------
// Flash attention (R12 body, proven 53.4us).  Grid (32, nb*12), 256 thr =
// 4 waves; wave owns 16 q rows.  KVBLK=64.  stageK(t+2) top / stageV(t+2)
// end, counted vmcnt(2).  Local-check defer-max, partial-l, unroll-2, zA/zB.
// ---------------------------------------------------------------------------
#define TRRD(dst, addr, OFF)                                                   \
  asm volatile("ds_read_b64_tr_b16 %0, %1 offset:" #OFF                        \
               : "=v"(dst) : "v"(addr))

__global__ __launch_bounds__(256) void attn_kernel(const short* __restrict__ qkv,
                                                   short* __restrict__ obuf) {
  __shared__ __align__(16) short Ks[2][64 * 64];
  __shared__ __align__(16) short Vt[2][64 * 64];
  __shared__ __align__(16) short Ps[4][16 * 64];
  const int tid  = threadIdx.x;
  const int lane = tid & 63, w = tid >> 6;
  const int g = lane >> 4, li = lane & 15;
  const unsigned o = xcd_swz(blockIdx.y * 32u + blockIdx.x, gridDim.x * gridDim.y);
  const int bh = (int)(o >> 5);
  const int b = bh / Hh, h = bh % Hh;
  const size_t rowbase = (size_t)b * Ll * N1;
  const int q0 = (int)(o & 31u) * 64 + w * 16;
  constexpr float kScale = 0.125f * 1.44269504f;   // 1/sqrt(Dh) * log2(e)
  constexpr float kThrRaw = 8.f / kScale;          // defer-max threshold (raw)
  constexpr int KVSTRIDE = 64 * N1;                // elements per KV tile

  // Q fragments (B operand of swapped QK^T)
  s16x8 qf[2];
#pragma unroll
  for (int ks = 0; ks < 2; ++ks)
    qf[ks] = *(const s16x8*)(qkv + rowbase + (size_t)(q0 + li) * N1 +
                             h * Dh + ks * 32 + g * 8);

  f32x4 oa[4];
  float m_ = -1e30f, l_ = 0.f;   // m_ row-uniform (raw); l_ per-lane PARTIAL
#pragma unroll
  for (int dn = 0; dn < 4; ++dn)
#pragma unroll
    for (int r = 0; r < 4; ++r) oa[dn][r] = 0.f;

  constexpr int NT = Ll / 64;  // 32 tiles

  // ---- hoisted staging source pointers (advance per stage call) ----
  const int ia = tid, ib = 256 + tid;
  const int ra = ia >> 3, ca = ia & 7, rb = ib >> 3, cb = ib & 7;
  const short* kpa = qkv + rowbase + Dd + h * Dh + (size_t)ra * N1 + (ca ^ (ra & 7)) * 8;
  const short* kpb = qkv + rowbase + Dd + h * Dh + (size_t)rb * N1 + (cb ^ (rb & 7)) * 8;
  const int Ta = ia >> 3, Tb = ib >> 3;
  const short* vpa = qkv + rowbase + 2 * Dd + h * Dh +
                     (size_t)((Ta & 15) * 4 + (ca >> 1)) * N1 + (Ta >> 4) * 16 + (ia & 1) * 8;
  const short* vpb = qkv + rowbase + 2 * Dd + h * Dh +
                     (size_t)((Tb & 15) * 4 + (cb >> 1)) * N1 + (Tb >> 4) * 16 + (ib & 1) * 8;
  char* KsB = (char*)&Ks[0][0];
  char* VtB = (char*)&Vt[0][0];
  const int dsta = ia * 16, dstb = ib * 16;

  // ---- hoisted LDS fragment offsets (bytes) ----
  int koff[4][2];
#pragma unroll
  for (int n = 0; n < 4; ++n) {
    koff[n][0] = ((n * 16 + li) * 64 + ((g ^ (li & 7)) & 7) * 8) * 2;
    koff[n][1] = ((n * 16 + li) * 64 + (((4 + g) ^ (li & 7)) & 7) * 8) * 2;
  }
  int pwoff[4], proff[2];
#pragma unroll
  for (int n = 0; n < 4; ++n)
    pwoff[n] = li * 128 + (((2 * n + (g >> 1)) ^ (li & 7)) << 4) + 8 * (g & 1);
#pragma unroll
  for (int kk = 0; kk < 2; ++kk)
    proff[kk] = li * 128 + (((4 * kk + g) ^ (li & 7)) << 4);
  char* Pw = (char*)&Ps[w][0];
  const unsigned vlane = (unsigned)((lane >> 4) * 256 + (lane & 15) * 2);
  const unsigned vbase0 = (unsigned)(unsigned long long)(&Vt[0][0]) + vlane;

  auto stageK = [&](int buf) {
    const int bo = buf << 13;
    gload_lds16(kpa, KsB + bo + dsta);
    gload_lds16(kpb, KsB + bo + dstb);
    kpa += KVSTRIDE; kpb += KVSTRIDE;
  };
  auto stageV = [&](int buf) {
    const int bo = buf << 13;
    gload_lds16(vpa, VtB + bo + dsta);
    gload_lds16(vpb, VtB + bo + dstb);
    vpa += KVSTRIDE; vpb += KVSTRIDE;
  };

  // prologue: K0 V0 K1 V1 (8 loads); wait K0+V0, leave K1+V1 in flight
  stageK(0); stageV(0); stageK(1); stageV(1);
  asm volatile("s_waitcnt vmcnt(4)" ::: "memory");
  __builtin_amdgcn_s_barrier();
  __builtin_amdgcn_sched_barrier(0);

  f32x4 zA[4], zB[4];
#pragma unroll
  for (int n = 0; n < 4; ++n) {
    s16x8 kf0 = *(const s16x8*)(KsB + koff[n][0]);
    s16x8 kf1 = *(const s16x8*)(KsB + koff[n][1]);
    f32x4 z;
#pragma unroll
    for (int r = 0; r < 4; ++r) z[r] = 0.f;
    z = mfma16(kf0, qf[0], z);
    z = mfma16(kf1, qf[1], z);
    zA[n] = z;
  }

  // one iteration body: tile t (buffer cur), scores in zC; computes zN for t+1
  auto body = [&](int kt, int cur, f32x4 (&zC)[4], f32x4 (&zN)[4]) {
    const int curo = cur << 13;
    const int nxto = (cur ^ 1) << 13;
    if (kt + 1 < NT) asm volatile("s_waitcnt vmcnt(2)" ::: "memory");
    else             asm volatile("s_waitcnt vmcnt(0)" ::: "memory");
    __builtin_amdgcn_s_barrier();
    __builtin_amdgcn_sched_barrier(0);

    if (kt + 2 < NT) stageK(cur);

    if (kt + 1 < NT) {
      __builtin_amdgcn_s_setprio(1);
#pragma unroll
      for (int n = 0; n < 4; ++n) {
        s16x8 kf0 = *(const s16x8*)(KsB + nxto + koff[n][0]);
        s16x8 kf1 = *(const s16x8*)(KsB + nxto + koff[n][1]);
        f32x4 z;
#pragma unroll
        for (int r = 0; r < 4; ++r) z[r] = 0.f;
        z = mfma16(kf0, qf[0], z);
        z = mfma16(kf1, qf[1], z);
        zN[n] = z;
      }
      __builtin_amdgcn_s_setprio(0);
    }

    // ---- softmax on zC: per-lane local max checks the defer branch ----
    const float t0 = fmaxf(fmaxf(zC[0][0], zC[0][1]), zC[0][2]);
    const float t1 = fmaxf(fmaxf(zC[0][3], zC[1][0]), zC[1][1]);
    const float t2 = fmaxf(fmaxf(zC[1][2], zC[1][3]), zC[2][0]);
    const float t3 = fmaxf(fmaxf(zC[2][1], zC[2][2]), zC[2][3]);
    const float t4 = fmaxf(fmaxf(zC[3][0], zC[3][1]), zC[3][2]);
    const float mloc = fmaxf(fmaxf(fmaxf(fmaxf(t0, t1), t2), fmaxf(t3, t4)), zC[3][3]);
    if (!__all(mloc - m_ <= kThrRaw)) {
      const float mxr = redmax64(mloc);          // full row max (rare path)
      const float mnew = fmaxf(m_, mxr);
      const float sc = fexp2((m_ - mnew) * kScale);
      float scq[4];
#pragma unroll
      for (int r = 0; r < 4; ++r)
        scq[r] = __shfl(sc, (lane & 48) + ((lane & 48) >> 2) + r, 64);
#pragma unroll
      for (int dn = 0; dn < 4; ++dn)
#pragma unroll
        for (int r = 0; r < 4; ++r) oa[dn][r] *= scq[r];
      l_ *= sc;                                   // partial scaled by row-uniform sc
      m_ = mnew;
    }
    const float msc = m_ * kScale;
#pragma unroll
    for (int n = 0; n < 4; ++n)
#pragma unroll
      for (int r = 0; r < 4; ++r) {
        const float p = fexp2(fmaf(zC[n][r], kScale, -msc));
        zC[n][r] = p;
        l_ += p;                                  // per-lane partial sum
      }

    // ---- P pack via cvt_pk -> swizzled per-wave LDS (4 x ds_write_b64) ----
#pragma unroll
    for (int n = 0; n < 4; ++n) {
      unsigned u0, u1;
      asm("v_cvt_pk_bf16_f32 %0, %1, %2" : "=v"(u0) : "v"(zC[n][0]), "v"(zC[n][1]));
      asm("v_cvt_pk_bf16_f32 %0, %1, %2" : "=v"(u1) : "v"(zC[n][2]), "v"(zC[n][3]));
      i32x2 pv; pv[0] = (int)u0; pv[1] = (int)u1;
      *(i32x2*)(Pw + pwoff[n]) = pv;
    }

    s16x8 pf[2];
#pragma unroll
    for (int kk = 0; kk < 2; ++kk)
      pf[kk] = *(const s16x8*)(Pw + proff[kk]);

    union VU { long l[2]; s16x8 v; };
    VU vu[4][2];
    {
      const unsigned vaddr = vbase0 + (unsigned)curo;
      TRRD(vu[0][0].l[0], vaddr, 0);    TRRD(vu[0][0].l[1], vaddr, 128);
      TRRD(vu[0][1].l[0], vaddr, 1024); TRRD(vu[0][1].l[1], vaddr, 1152);
      TRRD(vu[1][0].l[0], vaddr, 2048); TRRD(vu[1][0].l[1], vaddr, 2176);
      TRRD(vu[1][1].l[0], vaddr, 3072); TRRD(vu[1][1].l[1], vaddr, 3200);
      TRRD(vu[2][0].l[0], vaddr, 4096); TRRD(vu[2][0].l[1], vaddr, 4224);
      TRRD(vu[2][1].l[0], vaddr, 5120); TRRD(vu[2][1].l[1], vaddr, 5248);
      TRRD(vu[3][0].l[0], vaddr, 6144); TRRD(vu[3][0].l[1], vaddr, 6272);
      TRRD(vu[3][1].l[0], vaddr, 7168); TRRD(vu[3][1].l[1], vaddr, 7296);
    }
    asm volatile("s_waitcnt lgkmcnt(0)" ::: "memory");
    __builtin_amdgcn_sched_barrier(0);

    __builtin_amdgcn_s_setprio(1);
#pragma unroll
    for (int dn = 0; dn < 4; ++dn) {
      oa[dn] = mfma16(pf[0], vu[dn][0].v, oa[dn]);
      oa[dn] = mfma16(pf[1], vu[dn][1].v, oa[dn]);
    }
    __builtin_amdgcn_s_setprio(0);

    __builtin_amdgcn_s_barrier();
    if (kt + 2 < NT) stageV(cur);
  };

  // unrolled x2: even tile uses buf0 (zA->zB), odd tile buf1 (zB->zA)
  for (int g2 = 0; g2 < NT / 2; ++g2) {
    body(2 * g2,     0, zA, zB);
    body(2 * g2 + 1, 1, zB, zA);
  }

  // ---- epilogue: one cross-lane sum, then O / l -> bf16 obuf ----
  l_ = redsum64(l_);
  {
#pragma unroll
    for (int r = 0; r < 4; ++r) {
      const float lq = __shfl(l_, (lane & 48) + ((lane & 48) >> 2) + r, 64);
      const float inv = frcp(lq);
      const int row = b * Ll + q0 + g * 4 + r;
#pragma unroll
      for (int dn = 0; dn < 4; ++dn)
        obuf[(size_t)row * Dd + h * Dh + dn * 16 + li] =
            (short)f2bf(oa[dn][r] * inv);
    }
  }
}

// ---------------------------------------------------------------------------
extern "C" void kernel_launch(void* const* d_in, const int* in_sizes, int n_in,
                              void* d_out, int out_size, void* d_ws, size_t ws_size,
                              hipStream_t stream) {
  const float* x     = (const float*)d_in[0];
  const float* gamma = (const float*)d_in[1];
  const float* beta  = (const float*)d_in[2];
  const float* w1    = (const float*)d_in[3];
  const float* b1    = (const float*)d_in[4];
  const float* w2    = (const float*)d_in[5];
  const float* b2    = (const float*)d_in[6];
  float* out = (float*)d_out;
  char* ws = (char*)d_ws;

  if (ws_size >= 29884416) {
    // ---- T1: full batch in one pass.  ws = 29,884,416 B ----
    short* qkvb = (short*)(ws);              // 4096*2304*2 = 18874368
    short* hb   = (short*)(ws + 18874368);   // 4096*768*2  = 6291456 (hbuf, then obuf)
    short* w1b  = (short*)(ws + 25165824);   // 2304*768*2  = 3538944
    short* w2b  = (short*)(ws + 28704768);   // 768*768*2   = 1179648
    prep_kernel<<<dim3(Mrows + 1024), dim3(256), 0, stream>>>(
        x, gamma, beta, hb, w1, w2, w1b, w2b);
    gemm_bt<0, 0><<<dim3(N1 / 128, Mrows / 128), dim3(256), 0, stream>>>(
        hb, w1b, b1, nullptr, (void*)qkvb, N1, Dd);
    attn_kernel<<<dim3(Ll / 64, Bb * Hh), dim3(256), 0, stream>>>(qkvb, hb);
    gemm_bt<1, 0><<<dim3(Dd / 128, Mrows / 128), dim3(256), 0, stream>>>(
        hb, w2b, b2, x, (void*)out, Dd, Dd);
  } else if (ws_size >= 17301504) {
    // ---- T2: per-batch, bf16 weights.  ws = 17,301,504 B ----
    short* qkvb = (short*)(ws);              // 2048*2304*2 = 9437184
    short* hb   = (short*)(ws + 9437184);    // 2048*768*2  = 3145728 (hbuf/obuf)
    short* w1b  = (short*)(ws + 12582912);   // 3538944
    short* w2b  = (short*)(ws + 16121856);   // 1179648
    cvt_kernel<<<dim3(1024), dim3(256), 0, stream>>>(w1, w2, w1b, w2b);
    for (int b = 0; b < Bb; ++b) {
      const size_t ro = (size_t)b * Ll * Dd;
      ln_kernel<<<dim3(Ll), dim3(256), 0, stream>>>(x + ro, gamma, beta, hb);
      gemm_bt<0, 0><<<dim3(N1 / 128, Ll / 128), dim3(256), 0, stream>>>(
          hb, w1b, b1, nullptr, (void*)qkvb, N1, Dd);
      attn_kernel<<<dim3(Ll / 64, Hh), dim3(256), 0, stream>>>(qkvb, hb);
      gemm_bt<1, 0><<<dim3(Dd / 128, Ll / 128), dim3(256), 0, stream>>>(
          hb, w2b, b2, x + ro, (void*)(out + ro), Dd, Dd);
    }
  } else {
    // ---- T3: per-batch, fp32 weights staged on the fly.  ws = 12,582,912 B ----
    short* qkvb = (short*)(ws);              // 9437184
    short* hb   = (short*)(ws + 9437184);    // 3145728 (hbuf/obuf)
    for (int b = 0; b < Bb; ++b) {
      const size_t ro = (size_t)b * Ll * Dd;
      ln_kernel<<<dim3(Ll), dim3(256), 0, stream>>>(x + ro, gamma, beta, hb);
      gemm_bt<0, 1><<<dim3(N1 / 128, Ll / 128), dim3(256), 0, stream>>>(
          hb, w1, b1, nullptr, (void*)qkvb, N1, Dd);
      attn_kernel<<<dim3(Ll / 64, Hh), dim3(256), 0, stream>>>(qkvb, hb);
      gemm_bt<1, 1><<<dim3(Dd / 128, Ll / 128), dim3(256), 0, stream>>>(
          hb, w2, b2, x + ro, (void*)(out + ro), Dd, Dd);
    }
  }
}

// Round 18
// 99.051 us; speedup vs baseline: 1.1785x; 1.0129x over previous
//
#include <hip/hip_runtime.h>

// ---------------------------------------------------------------------------
// Fused pre-LN MHA block on MI355X (gfx950).
// B=2, L=2048, D=768, H=12, Dh=64.
// Pipeline: prep(LN+cvt) -> GEMM1 (qkv) -> flash-attn -> GEMM2+residual
// R17: attn single-barrier-per-tile — V triple-buffered (rotating offset) so
// stageV issues at TOP next to stageK; bottom barrier deleted (64->32
// barriers/block).  Race audit: between barriers t and t+1, reads are
// K[cur^1], V[t%3], own Ps; writes are K[cur] (tile t+2), V[(t+2)%3], own
// Ps -- all disjoint.  vmcnt(2) still covers K(t+1)+V(t) at each wait.
// GEMMs (BK=32 dbuf) + vectorized cvt unchanged (proven R16).
// ---------------------------------------------------------------------------

#define DEV __device__ __forceinline__

typedef __attribute__((ext_vector_type(4))) float f32x4;
typedef __attribute__((ext_vector_type(8))) short s16x8;
typedef __attribute__((ext_vector_type(2))) int i32x2;

constexpr int Bb   = 2;
constexpr int Ll   = 2048;
constexpr int Dd   = 768;
constexpr int Hh   = 12;
constexpr int Dh   = 64;
constexpr int Mrows = Bb * Ll;      // 4096
constexpr int N1   = 3 * Dd;        // 2304

DEV unsigned short f2bf(float f) {
  union { float f; unsigned u; } v; v.f = f;
  unsigned r = v.u + 0x7fffu + ((v.u >> 16) & 1u);
  return (unsigned short)(r >> 16);
}

DEV void gload_lds16(const void* g, void* l) {
  __builtin_amdgcn_global_load_lds((const __attribute__((address_space(1))) unsigned int*)g,
                                   (__attribute__((address_space(3))) unsigned int*)l,
                                   16, 0, 0);
}

DEV f32x4 mfma16(s16x8 a, s16x8 b, f32x4 c) {
  return __builtin_amdgcn_mfma_f32_16x16x32_bf16(a, b, c, 0, 0, 0);
}

// single-instruction 2^x and 1/x
DEV float fexp2(float x) { float r; asm("v_exp_f32 %0, %1" : "=v"(r) : "v"(x)); return r; }
DEV float frcp(float x)  { float r; asm("v_rcp_f32 %0, %1" : "=v"(r) : "v"(x)); return r; }

// reduce over lanes {l, l^16, l^32, l^48}: shfl for xor16, permlane32 for xor32
DEV float redmax64(float x) {
  x = fmaxf(x, __shfl_xor(x, 16, 64));
  float a = x, b = x;
  asm volatile("v_permlane32_swap_b32 %0, %1" : "+v"(a), "+v"(b));
  return fmaxf(a, b);
}
DEV float redsum64(float x) {
  x += __shfl_xor(x, 16, 64);
  float a = x, b = x;
  asm volatile("v_permlane32_swap_b32 %0, %1" : "+v"(a), "+v"(b));
  return a + b;
}

// ---------------------------------------------------------------------------
// LN body (one block per row, 256 thr)
// ---------------------------------------------------------------------------
DEV void ln_body(int row, int t, const float* __restrict__ x,
                 const float* __restrict__ gamma, const float* __restrict__ beta,
                 short* __restrict__ hbuf, float* red) {
  const float* xr = x + (size_t)row * Dd;
  float v0 = xr[t], v1 = xr[t + 256], v2 = xr[t + 512];
  float s = v0 + v1 + v2;
  float q = v0 * v0 + v1 * v1 + v2 * v2;
#pragma unroll
  for (int off = 32; off; off >>= 1) {
    s += __shfl_xor(s, off, 64);
    q += __shfl_xor(q, off, 64);
  }
  const int w = t >> 6, lane = t & 63;
  if (lane == 0) { red[w] = s; red[4 + w] = q; }
  __syncthreads();
  s = red[0] + red[1] + red[2] + red[3];
  q = red[4] + red[5] + red[6] + red[7];
  const float mean = s * (1.f / Dd);
  const float var  = q * (1.f / Dd) - mean * mean;
  const float rstd = rsqrtf(var + 1e-5f);
  short* hr = hbuf + (size_t)row * Dd;
  hr[t]       = (short)f2bf((v0 - mean) * rstd * gamma[t]       + beta[t]);
  hr[t + 256] = (short)f2bf((v1 - mean) * rstd * gamma[t + 256] + beta[t + 256]);
  hr[t + 512] = (short)f2bf((v2 - mean) * rstd * gamma[t + 512] + beta[t + 512]);
}

constexpr int W1E = N1 * Dd;     // 1769472
constexpr int W2E = Dd * Dd;     // 589824
constexpr int WV4 = (W1E + W2E) / 4;   // 589824 float4 groups (W1E%4==0)

// vectorized weight cvt body: float4 load, 2x cvt_pk, 8B store
DEV void cvt_v4(int i, const float* __restrict__ w1, const float* __restrict__ w2,
                short* __restrict__ w1b, short* __restrict__ w2b) {
  const int e = i * 4;
  const float* src = (e < W1E) ? (w1 + e) : (w2 + (e - W1E));
  short* dst       = (e < W1E) ? (w1b + e) : (w2b + (e - W1E));
  const f32x4 v = *(const f32x4*)src;
  unsigned u01, u23;
  asm("v_cvt_pk_bf16_f32 %0, %1, %2" : "=v"(u01) : "v"(v[0]), "v"(v[1]));
  asm("v_cvt_pk_bf16_f32 %0, %1, %2" : "=v"(u23) : "v"(v[2]), "v"(v[3]));
  i32x2 o; o[0] = (int)u01; o[1] = (int)u23;
  *(i32x2*)dst = o;
}

__global__ __launch_bounds__(256) void ln_kernel(const float* __restrict__ x,
                                                 const float* __restrict__ gamma,
                                                 const float* __restrict__ beta,
                                                 short* __restrict__ hbuf) {
  __shared__ float red[8];
  ln_body(blockIdx.x, threadIdx.x, x, gamma, beta, hbuf, red);
}

__global__ __launch_bounds__(256) void cvt_kernel(const float* __restrict__ w1,
                                                  const float* __restrict__ w2,
                                                  short* __restrict__ w1b,
                                                  short* __restrict__ w2b) {
  int i = blockIdx.x * 256 + threadIdx.x;
  const int stride = gridDim.x * 256;
  for (; i < WV4; i += stride) cvt_v4(i, w1, w2, w1b, w2b);
}

// fused LN (blocks 0..Mrows-1) + weight cvt (blocks Mrows..Mrows+1023)
__global__ __launch_bounds__(256) void prep_kernel(const float* __restrict__ x,
                                                   const float* __restrict__ gamma,
                                                   const float* __restrict__ beta,
                                                   short* __restrict__ hbuf,
                                                   const float* __restrict__ w1,
                                                   const float* __restrict__ w2,
                                                   short* __restrict__ w1b,
                                                   short* __restrict__ w2b) {
  __shared__ float red[8];
  if (blockIdx.x < (unsigned)Mrows) {
    ln_body(blockIdx.x, threadIdx.x, x, gamma, beta, hbuf, red);
  } else {
    int i = (blockIdx.x - Mrows) * 256 + threadIdx.x;
    for (; i < WV4; i += 1024 * 256) cvt_v4(i, w1, w2, w1b, w2b);
  }
}

// XCD-aware chunked swizzle of the linear block id (bijective when nwg%8==0).
DEV unsigned xcd_swz(unsigned f, unsigned nwg) {
  if ((nwg & 7u) != 0u) return f;
  return (f & 7u) * (nwg >> 3) + (f >> 3);
}

// ---------------------------------------------------------------------------
// GEMM (B^T form): C[m][n] = sum_k A[m][k] * W[n][k] (+bias)(+resid)
// 128x128 tile, 4 waves (2x2).
// WSRC 0: BK=32 double-buffered (32KB LDS -> 4 blocks/CU), counted vmcnt(4).
// WSRC 1 (fp32 weights, T3 tier): BK=64 single-buffer __syncthreads loop.
// ---------------------------------------------------------------------------
template <int EPI, int WSRC>
__global__ __launch_bounds__(256) void gemm_bt(const short* __restrict__ A,
                                               const void* __restrict__ Wp,
                                               const float* __restrict__ bias,
                                               const float* __restrict__ resid,
                                               void* __restrict__ outp,
                                               int N, int K) {
  __shared__ __align__(16) short As[2][WSRC == 0 ? 128 * 32 : 128 * 64];
  __shared__ __align__(16) short Ws[2][WSRC == 0 ? 128 * 32 : 128 * 64];
  const int tid  = threadIdx.x;
  const int lane = tid & 63, wid = tid >> 6;
  const int wr = wid >> 1, wc = wid & 1;
  const int g = lane >> 4, li = lane & 15;
  const unsigned o = xcd_swz(blockIdx.y * gridDim.x + blockIdx.x,
                             gridDim.x * gridDim.y);
  const int brow = (int)(o / gridDim.x) * 128, bcol = (int)(o % gridDim.x) * 128;

  f32x4 acc[4][4];
#pragma unroll
  for (int m = 0; m < 4; ++m)
#pragma unroll
    for (int n = 0; n < 4; ++n)
#pragma unroll
      for (int r = 0; r < 4; ++r) acc[m][n][r] = 0.f;

  if constexpr (WSRC == 0) {
    const short* W = (const short*)Wp;
    const int nt = K >> 5;                      // BK=32 tiles
    auto stage = [&](int t, int buf) {
      const int ko = t << 5;
#pragma unroll
      for (int i = 0; i < 2; ++i) {
        const int idx = i * 256 + tid;          // 0..511
        const int r = idx >> 2, c = idx & 3;
        const int cs = c ^ ((r >> 1) & 3);
        gload_lds16(A + (size_t)(brow + r) * K + ko + cs * 8,
                    (char*)&As[buf][0] + idx * 16);
        gload_lds16(W + (size_t)(bcol + r) * K + ko + cs * 8,
                    (char*)&Ws[buf][0] + idx * 16);
      }
    };
    stage(0, 0);
    stage(1, 1);
    for (int it = 0; it < nt; ++it) {
      const int cur = it & 1;
      if (it + 1 < nt) asm volatile("s_waitcnt vmcnt(4)" ::: "memory");
      else             asm volatile("s_waitcnt vmcnt(0)" ::: "memory");
      __builtin_amdgcn_s_barrier();
      __builtin_amdgcn_sched_barrier(0);
      {
        s16x8 af[4], bf[4];
        const int rsw = ((li >> 1) & 3);
#pragma unroll
        for (int m = 0; m < 4; ++m) {
          const int row = wr * 64 + m * 16 + li;
          af[m] = *(const s16x8*)((char*)&As[cur][0] + row * 64 + ((g ^ rsw) << 4));
        }
#pragma unroll
        for (int n = 0; n < 4; ++n) {
          const int row = wc * 64 + n * 16 + li;
          bf[n] = *(const s16x8*)((char*)&Ws[cur][0] + row * 64 + ((g ^ rsw) << 4));
        }
#pragma unroll
        for (int m = 0; m < 4; ++m)
#pragma unroll
          for (int n = 0; n < 4; ++n)
            acc[m][n] = mfma16(af[m], bf[n], acc[m][n]);
      }
      __builtin_amdgcn_s_barrier();
      if (it + 2 < nt) stage(it + 2, cur);
    }
  } else {
    const float* W = (const float*)Wp;
    for (int kt = 0; kt < K; kt += 64) {
#pragma unroll
      for (int i = 0; i < 4; ++i) {
        const int idx = i * 256 + tid;
        const int r = idx >> 3, c = idx & 7;
        const int cs = c ^ (r & 7);
        gload_lds16(A + (size_t)(brow + r) * K + kt + cs * 8,
                    (char*)&As[0][0] + idx * 16);
      }
#pragma unroll
      for (int i = 0; i < 4; ++i) {
        const int idx = i * 256 + tid;
        const int r = idx >> 3, c = idx & 7;
        const float* wp = W + (size_t)(bcol + r) * K + kt + c * 8;
        const f32x4 lo = *(const f32x4*)wp;
        const f32x4 hi = *(const f32x4*)(wp + 4);
        s16x8 oo;
#pragma unroll
        for (int j = 0; j < 4; ++j) {
          oo[j]     = (short)f2bf(lo[j]);
          oo[4 + j] = (short)f2bf(hi[j]);
        }
        *(s16x8*)((char*)&Ws[0][0] + (size_t)(r * 8 + (c ^ (r & 7))) * 16) = oo;
      }
      __syncthreads();
#pragma unroll
      for (int kk = 0; kk < 2; ++kk) {
        s16x8 af[4], bf[4];
#pragma unroll
        for (int m = 0; m < 4; ++m) {
          const int row = wr * 64 + m * 16 + li;
          af[m] = *(const s16x8*)&As[0][row * 64 + (((kk * 4 + g) ^ (li & 7)) & 7) * 8];
        }
#pragma unroll
        for (int n = 0; n < 4; ++n) {
          const int row = wc * 64 + n * 16 + li;
          bf[n] = *(const s16x8*)&Ws[0][row * 64 + (((kk * 4 + g) ^ (li & 7)) & 7) * 8];
        }
#pragma unroll
        for (int m = 0; m < 4; ++m)
#pragma unroll
          for (int n = 0; n < 4; ++n)
            acc[m][n] = mfma16(af[m], bf[n], acc[m][n]);
      }
      __syncthreads();
    }
  }

#pragma unroll
  for (int m = 0; m < 4; ++m) {
#pragma unroll
    for (int n = 0; n < 4; ++n) {
      const int col = bcol + wc * 64 + n * 16 + li;
      const float bv = bias[col];
#pragma unroll
      for (int r = 0; r < 4; ++r) {
        const int row = brow + wr * 64 + m * 16 + g * 4 + r;
        const float v = acc[m][n][r] + bv;
        if (EPI == 0) {
          ((short*)outp)[(size_t)row * N + col] = (short)f2bf(v);
        } else {
          const size_t o2 = (size_t)row * N + col;
          ((float*)outp)[o2] = v + resid[o2];
        }
      }
    }
  }
}

// ---------------------------------------------------------------------------
// Flash attention R17 (= R12 body + triple-buffered V + single barrier/tile).
// Grid (32, nb*12), 256 thr = 4 waves; wave owns 16 q rows.  KVBLK=64.
// Per tile: vmcnt(2) -> barrier -> stageK(t+2)+stageV(t+2) -> zB -> softmax
// -> P -> TRRD V[t%3] -> PV.  No bottom barrier (write/read sets disjoint).
// ---------------------------------------------------------------------------
#define TRRD(dst, addr, OFF)                                                   \
  asm volatile("ds_read_b64_tr_b16 %0, %1 offset:" #OFF                        \
               : "=v"(dst) : "v"(addr))

__global__ __launch_bounds__(256) void attn_kernel(const short* __restrict__ qkv,
                                                   short* __restrict__ obuf) {
  __shared__ __align__(16) short Ks[2][64 * 64];
  __shared__ __align__(16) short Vt[3][64 * 64];   // triple-buffered
  __shared__ __align__(16) short Ps[4][16 * 64];
  const int tid  = threadIdx.x;
  const int lane = tid & 63, w = tid >> 6;
  const int g = lane >> 4, li = lane & 15;
  const unsigned o = xcd_swz(blockIdx.y * 32u + blockIdx.x, gridDim.x * gridDim.y);
  const int bh = (int)(o >> 5);
  const int b = bh / Hh, h = bh % Hh;
  const size_t rowbase = (size_t)b * Ll * N1;
  const int q0 = (int)(o & 31u) * 64 + w * 16;
  constexpr float kScale = 0.125f * 1.44269504f;   // 1/sqrt(Dh) * log2(e)
  constexpr float kThrRaw = 8.f / kScale;          // defer-max threshold (raw)
  constexpr int KVSTRIDE = 64 * N1;                // elements per KV tile
  constexpr int VBUF = 8192;                       // bytes per V buffer

  // Q fragments (B operand of swapped QK^T)
  s16x8 qf[2];
#pragma unroll
  for (int ks = 0; ks < 2; ++ks)
    qf[ks] = *(const s16x8*)(qkv + rowbase + (size_t)(q0 + li) * N1 +
                             h * Dh + ks * 32 + g * 8);

  f32x4 oa[4];
  float m_ = -1e30f, l_ = 0.f;   // m_ row-uniform (raw); l_ per-lane PARTIAL
#pragma unroll
  for (int dn = 0; dn < 4; ++dn)
#pragma unroll
    for (int r = 0; r < 4; ++r) oa[dn][r] = 0.f;

  constexpr int NT = Ll / 64;  // 32 tiles

  // ---- hoisted staging source pointers (advance per stage call) ----
  const int ia = tid, ib = 256 + tid;
  const int ra = ia >> 3, ca = ia & 7, rb = ib >> 3, cb = ib & 7;
  const short* kpa = qkv + rowbase + Dd + h * Dh + (size_t)ra * N1 + (ca ^ (ra & 7)) * 8;
  const short* kpb = qkv + rowbase + Dd + h * Dh + (size_t)rb * N1 + (cb ^ (rb & 7)) * 8;
  const int Ta = ia >> 3, Tb = ib >> 3;
  const short* vpa = qkv + rowbase + 2 * Dd + h * Dh +
                     (size_t)((Ta & 15) * 4 + (ca >> 1)) * N1 + (Ta >> 4) * 16 + (ia & 1) * 8;
  const short* vpb = qkv + rowbase + 2 * Dd + h * Dh +
                     (size_t)((Tb & 15) * 4 + (cb >> 1)) * N1 + (Tb >> 4) * 16 + (ib & 1) * 8;
  char* KsB = (char*)&Ks[0][0];
  char* VtB = (char*)&Vt[0][0];
  const int dsta = ia * 16, dstb = ib * 16;

  // ---- hoisted LDS fragment offsets (bytes) ----
  int koff[4][2];
#pragma unroll
  for (int n = 0; n < 4; ++n) {
    koff[n][0] = ((n * 16 + li) * 64 + ((g ^ (li & 7)) & 7) * 8) * 2;
    koff[n][1] = ((n * 16 + li) * 64 + (((4 + g) ^ (li & 7)) & 7) * 8) * 2;
  }
  int pwoff[4], proff[2];
#pragma unroll
  for (int n = 0; n < 4; ++n)
    pwoff[n] = li * 128 + (((2 * n + (g >> 1)) ^ (li & 7)) << 4) + 8 * (g & 1);
#pragma unroll
  for (int kk = 0; kk < 2; ++kk)
    proff[kk] = li * 128 + (((4 * kk + g) ^ (li & 7)) << 4);
  char* Pw = (char*)&Ps[w][0];
  const unsigned vlane = (unsigned)((lane >> 4) * 256 + (lane & 15) * 2);
  const unsigned vbase0 = (unsigned)(unsigned long long)(&Vt[0][0]) + vlane;

  auto stageK = [&](int buf) {
    const int bo = buf << 13;
    gload_lds16(kpa, KsB + bo + dsta);
    gload_lds16(kpb, KsB + bo + dstb);
    kpa += KVSTRIDE; kpb += KVSTRIDE;
  };
  auto stageV = [&](int byteoff) {
    gload_lds16(vpa, VtB + byteoff + dsta);
    gload_lds16(vpb, VtB + byteoff + dstb);
    vpa += KVSTRIDE; vpb += KVSTRIDE;
  };

  // prologue: K0 V0 K1 V1 (8 loads); wait K0+V0, leave K1+V1 in flight
  stageK(0); stageV(0); stageK(1); stageV(VBUF);
  asm volatile("s_waitcnt vmcnt(4)" ::: "memory");
  __builtin_amdgcn_s_barrier();
  __builtin_amdgcn_sched_barrier(0);

  f32x4 zA[4], zB[4];
#pragma unroll
  for (int n = 0; n < 4; ++n) {
    s16x8 kf0 = *(const s16x8*)(KsB + koff[n][0]);
    s16x8 kf1 = *(const s16x8*)(KsB + koff[n][1]);
    f32x4 z;
#pragma unroll
    for (int r = 0; r < 4; ++r) z[r] = 0.f;
    z = mfma16(kf0, qf[0], z);
    z = mfma16(kf1, qf[1], z);
    zA[n] = z;
  }

  int voff = 0;  // byte offset of V buffer holding the CURRENT tile

  // one iteration body: tile t (K buffer cur), scores in zC; zN for t+1
  auto body = [&](int kt, int cur, f32x4 (&zC)[4], f32x4 (&zN)[4]) {
    const int nxto = (cur ^ 1) << 13;
    if (kt + 1 < NT) asm volatile("s_waitcnt vmcnt(2)" ::: "memory");
    else             asm volatile("s_waitcnt vmcnt(0)" ::: "memory");
    __builtin_amdgcn_s_barrier();
    __builtin_amdgcn_sched_barrier(0);

    if (kt + 2 < NT) {
      stageK(cur);                                   // K tile kt+2 -> K[cur]
      const int vsto = (voff >= VBUF) ? voff - VBUF : voff + 2 * VBUF;
      stageV(vsto);                                  // V tile kt+2 -> V[(kt+2)%3]
    }

    if (kt + 1 < NT) {
      __builtin_amdgcn_s_setprio(1);
#pragma unroll
      for (int n = 0; n < 4; ++n) {
        s16x8 kf0 = *(const s16x8*)(KsB + nxto + koff[n][0]);
        s16x8 kf1 = *(const s16x8*)(KsB + nxto + koff[n][1]);
        f32x4 z;
#pragma unroll
        for (int r = 0; r < 4; ++r) z[r] = 0.f;
        z = mfma16(kf0, qf[0], z);
        z = mfma16(kf1, qf[1], z);
        zN[n] = z;
      }
      __builtin_amdgcn_s_setprio(0);
    }

    // ---- softmax on zC: per-lane local max checks the defer branch ----
    const float t0 = fmaxf(fmaxf(zC[0][0], zC[0][1]), zC[0][2]);
    const float t1 = fmaxf(fmaxf(zC[0][3], zC[1][0]), zC[1][1]);
    const float t2 = fmaxf(fmaxf(zC[1][2], zC[1][3]), zC[2][0]);
    const float t3 = fmaxf(fmaxf(zC[2][1], zC[2][2]), zC[2][3]);
    const float t4 = fmaxf(fmaxf(zC[3][0], zC[3][1]), zC[3][2]);
    const float mloc = fmaxf(fmaxf(fmaxf(fmaxf(t0, t1), t2), fmaxf(t3, t4)), zC[3][3]);
    if (!__all(mloc - m_ <= kThrRaw)) {
      const float mxr = redmax64(mloc);          // full row max (rare path)
      const float mnew = fmaxf(m_, mxr);
      const float sc = fexp2((m_ - mnew) * kScale);
      float scq[4];
#pragma unroll
      for (int r = 0; r < 4; ++r)
        scq[r] = __shfl(sc, (lane & 48) + ((lane & 48) >> 2) + r, 64);
#pragma unroll
      for (int dn = 0; dn < 4; ++dn)
#pragma unroll
        for (int r = 0; r < 4; ++r) oa[dn][r] *= scq[r];
      l_ *= sc;                                   // partial scaled by row-uniform sc
      m_ = mnew;
    }
    const float msc = m_ * kScale;
#pragma unroll
    for (int n = 0; n < 4; ++n)
#pragma unroll
      for (int r = 0; r < 4; ++r) {
        const float p = fexp2(fmaf(zC[n][r], kScale, -msc));
        zC[n][r] = p;
        l_ += p;                                  // per-lane partial sum
      }

    // ---- P pack via cvt_pk -> swizzled per-wave LDS (4 x ds_write_b64) ----
#pragma unroll
    for (int n = 0; n < 4; ++n) {
      unsigned u0, u1;
      asm("v_cvt_pk_bf16_f32 %0, %1, %2" : "=v"(u0) : "v"(zC[n][0]), "v"(zC[n][1]));
      asm("v_cvt_pk_bf16_f32 %0, %1, %2" : "=v"(u1) : "v"(zC[n][2]), "v"(zC[n][3]));
      i32x2 pv; pv[0] = (int)u0; pv[1] = (int)u1;
      *(i32x2*)(Pw + pwoff[n]) = pv;
    }

    s16x8 pf[2];
#pragma unroll
    for (int kk = 0; kk < 2; ++kk)
      pf[kk] = *(const s16x8*)(Pw + proff[kk]);

    union VU { long l[2]; s16x8 v; };
    VU vu[4][2];
    {
      const unsigned vaddr = vbase0 + (unsigned)voff;
      TRRD(vu[0][0].l[0], vaddr, 0);    TRRD(vu[0][0].l[1], vaddr, 128);
      TRRD(vu[0][1].l[0], vaddr, 1024); TRRD(vu[0][1].l[1], vaddr, 1152);
      TRRD(vu[1][0].l[0], vaddr, 2048); TRRD(vu[1][0].l[1], vaddr, 2176);
      TRRD(vu[1][1].l[0], vaddr, 3072); TRRD(vu[1][1].l[1], vaddr, 3200);
      TRRD(vu[2][0].l[0], vaddr, 4096); TRRD(vu[2][0].l[1], vaddr, 4224);
      TRRD(vu[2][1].l[0], vaddr, 5120); TRRD(vu[2][1].l[1], vaddr, 5248);
      TRRD(vu[3][0].l[0], vaddr, 6144); TRRD(vu[3][0].l[1], vaddr, 6272);
      TRRD(vu[3][1].l[0], vaddr, 7168); TRRD(vu[3][1].l[1], vaddr, 7296);
    }
    asm volatile("s_waitcnt lgkmcnt(0)" ::: "memory");
    __builtin_amdgcn_sched_barrier(0);

    __builtin_amdgcn_s_setprio(1);
#pragma unroll
    for (int dn = 0; dn < 4; ++dn) {
      oa[dn] = mfma16(pf[0], vu[dn][0].v, oa[dn]);
      oa[dn] = mfma16(pf[1], vu[dn][1].v, oa[dn]);
    }
    __builtin_amdgcn_s_setprio(0);

    // no bottom barrier: next iter's top barrier provides the sync; write
    // targets between consecutive barriers are disjoint from all read sets.
    voff = (voff == 2 * VBUF) ? 0 : voff + VBUF;
  };

  // unrolled x2 (K buffer period 2; V offset rotates mod 3 via voff)
  for (int g2 = 0; g2 < NT / 2; ++g2) {
    body(2 * g2,     0, zA, zB);
    body(2 * g2 + 1, 1, zB, zA);
  }

  // ---- epilogue: one cross-lane sum, then O / l -> bf16 obuf ----
  l_ = redsum64(l_);
  {
#pragma unroll
    for (int r = 0; r < 4; ++r) {
      const float lq = __shfl(l_, (lane & 48) + ((lane & 48) >> 2) + r, 64);
      const float inv = frcp(lq);
      const int row = b * Ll + q0 + g * 4 + r;
#pragma unroll
      for (int dn = 0; dn < 4; ++dn)
        obuf[(size_t)row * Dd + h * Dh + dn * 16 + li] =
            (short)f2bf(oa[dn][r] * inv);
    }
  }
}

// ---------------------------------------------------------------------------
extern "C" void kernel_launch(void* const* d_in, const int* in_sizes, int n_in,
                              void* d_out, int out_size, void* d_ws, size_t ws_size,
                              hipStream_t stream) {
  const float* x     = (const float*)d_in[0];
  const float* gamma = (const float*)d_in[1];
  const float* beta  = (const float*)d_in[2];
  const float* w1    = (const float*)d_in[3];
  const float* b1    = (const float*)d_in[4];
  const float* w2    = (const float*)d_in[5];
  const float* b2    = (const float*)d_in[6];
  float* out = (float*)d_out;
  char* ws = (char*)d_ws;

  if (ws_size >= 29884416) {
    // ---- T1: full batch in one pass.  ws = 29,884,416 B ----
    short* qkvb = (short*)(ws);              // 4096*2304*2 = 18874368
    short* hb   = (short*)(ws + 18874368);   // 4096*768*2  = 6291456 (hbuf, then obuf)
    short* w1b  = (short*)(ws + 25165824);   // 2304*768*2  = 3538944
    short* w2b  = (short*)(ws + 28704768);   // 768*768*2   = 1179648
    prep_kernel<<<dim3(Mrows + 1024), dim3(256), 0, stream>>>(
        x, gamma, beta, hb, w1, w2, w1b, w2b);
    gemm_bt<0, 0><<<dim3(N1 / 128, Mrows / 128), dim3(256), 0, stream>>>(
        hb, w1b, b1, nullptr, (void*)qkvb, N1, Dd);
    attn_kernel<<<dim3(Ll / 64, Bb * Hh), dim3(256), 0, stream>>>(qkvb, hb);
    gemm_bt<1, 0><<<dim3(Dd / 128, Mrows / 128), dim3(256), 0, stream>>>(
        hb, w2b, b2, x, (void*)out, Dd, Dd);
  } else if (ws_size >= 17301504) {
    // ---- T2: per-batch, bf16 weights.  ws = 17,301,504 B ----
    short* qkvb = (short*)(ws);              // 2048*2304*2 = 9437184
    short* hb   = (short*)(ws + 9437184);    // 2048*768*2  = 3145728 (hbuf/obuf)
    short* w1b  = (short*)(ws + 12582912);   // 3538944
    short* w2b  = (short*)(ws + 16121856);   // 1179648
    cvt_kernel<<<dim3(1024), dim3(256), 0, stream>>>(w1, w2, w1b, w2b);
    for (int b = 0; b < Bb; ++b) {
      const size_t ro = (size_t)b * Ll * Dd;
      ln_kernel<<<dim3(Ll), dim3(256), 0, stream>>>(x + ro, gamma, beta, hb);
      gemm_bt<0, 0><<<dim3(N1 / 128, Ll / 128), dim3(256), 0, stream>>>(
          hb, w1b, b1, nullptr, (void*)qkvb, N1, Dd);
      attn_kernel<<<dim3(Ll / 64, Hh), dim3(256), 0, stream>>>(qkvb, hb);
      gemm_bt<1, 0><<<dim3(Dd / 128, Ll / 128), dim3(256), 0, stream>>>(
          hb, w2b, b2, x + ro, (void*)(out + ro), Dd, Dd);
    }
  } else {
    // ---- T3: per-batch, fp32 weights staged on the fly.  ws = 12,582,912 B ----
    short* qkvb = (short*)(ws);              // 9437184
    short* hb   = (short*)(ws + 9437184);    // 3145728 (hbuf/obuf)
    for (int b = 0; b < Bb; ++b) {
      const size_t ro = (size_t)b * Ll * Dd;
      ln_kernel<<<dim3(Ll), dim3(256), 0, stream>>>(x + ro, gamma, beta, hb);
      gemm_bt<0, 1><<<dim3(N1 / 128, Ll / 128), dim3(256), 0, stream>>>(
          hb, w1, b1, nullptr, (void*)qkvb, N1, Dd);
      attn_kernel<<<dim3(Ll / 64, Hh), dim3(256), 0, stream>>>(qkvb, hb);
      gemm_bt<1, 1><<<dim3(Dd / 128, Ll / 128), dim3(256), 0, stream>>>(
          hb, w2, b2, x + ro, (void*)(out + ro), Dd, Dd);
    }
  }
}